// Round 5
// baseline (208.930 us; speedup 1.0000x reference)
//
#include <hip/hip_runtime.h>

#define BB   4
#define CC   256
#define HH   128
#define WW   128
#define PAD  4
#define KOUT 81
#define KC   32                   // channels per chunk (MFMA K)
#define NCC  (CC / KC)            // 8 chunks

#define TH   8                    // output rows per block (one per wave)
#define SW   16                   // output cols per block
#define AK   40                   // LDS K-stride per point in f16 (80 B)
#define BPTS 384                  // 16 rows x 24 q
#define APTS 128                  // 8 rows x 16 m

#define PLANE      ((size_t)HH * WW)            // 16384 pixels
#define CHPLANE    (PLANE * KC)                 // f16 elems per (b,cc) chunk-plane
#define SLOT_ELEMS ((size_t)BB * NCC * CHPLANE) // f16 elems per input slot (33.5 MB)

typedef _Float16 half8 __attribute__((ext_vector_type(8)));
typedef float    f32x4 __attribute__((ext_vector_type(4)));

// ---------------- Pass 1: NCHW f32 -> [input][b][cc][h][w][32c] f16 ----------
// One block = one (input, b, cc, h): 32 channels x 128 w.
__global__ __launch_bounds__(256)
void corr_pass1(const float* __restrict__ i1,
                const float* __restrict__ i2,
                _Float16* __restrict__ interm)
{
    __shared__ float tile[32 * 132];    // stride 132 dwords: b128 writes conflict-free

    const int t   = threadIdx.x;
    const int h   = blockIdx.x;
    const int cc  = blockIdx.y;
    const int zb  = blockIdx.z;         // input*4 + b
    const int inp = zb >> 2;
    const int b   = zb & 3;

    const float* src = (inp ? i2 : i1)
                     + ((size_t)b * CC + cc * KC) * PLANE + (size_t)h * WW;

    // ---- load: wave wv covers channels wv*8..wv*8+7; per instr lanes are
    //      w-contiguous (2 channels x full 512B row per instruction).
    {
        const int wv = t >> 6;
        const int ln = t & 63;
        const int cp = ln >> 5;          // channel parity within pair
        const int w4 = ln & 31;          // float4 index along row
#pragma unroll
        for (int k = 0; k < 4; ++k) {
            const int c = wv * 8 + 2 * k + cp;
            const float4 v = *(const float4*)(src + (size_t)c * PLANE + w4 * 4);
            *(float4*)&tile[c * 132 + w4 * 4] = v;
        }
    }
    __syncthreads();

    // ---- read+cvt+store: thread t -> pixel w = t>>1, half g = t&1 (16 ch)
    {
        const int w = t >> 1;
        const int g = t & 1;
        _Float16 o[16];
#pragma unroll
        for (int j = 0; j < 16; ++j)
            o[j] = (_Float16)tile[(g * 16 + j) * 132 + w];
        _Float16* dst = interm + (size_t)inp * SLOT_ELEMS
                      + ((size_t)(b * NCC + cc) * PLANE + (size_t)h * WW + w) * KC
                      + g * 16;
        *(half8*)&dst[0] = *(half8*)&o[0];
        *(half8*)&dst[8] = *(half8*)&o[8];
    }
}

// ---------------- Pass 2: banded MFMA correlation from f16 chunk-planes ------
__global__ __launch_bounds__(512)
void corr_pass2(const _Float16* __restrict__ interm,
                float* __restrict__ out)
{
    // B (384 pts) then A (128 pts), 80 B per point per chunk.
    // B frag reads for q>=24 spill into the A region: finite garbage feeding
    // only dx>8 output columns, which are never stored.
    __shared__ _Float16 sh[(BPTS + APTS) * AK];   // 40960 B

    const int t    = threadIdx.x;
    const int wave = t >> 6;
    const int lane = t & 63;
    const int l15  = lane & 15;
    const int quad = lane >> 4;

    const int b  = blockIdx.z;
    const int h0 = blockIdx.y * TH;
    const int w0 = blockIdx.x * SW;

    // ---- staging role: one point per thread, 64 B (4 x dwordx4) per chunk.
    const bool isB = (t < BPTS);
    bool valid;
    size_t pixoff;                       // f16-element offset of point's K-run
    _Float16* ldst;
    const _Float16* gbase;               // chunk-0 base (uniform per role)
    if (isB) {
        const int sq  = t % 24;
        const int sr  = t / 24;
        const int col = w0 - PAD + sq;
        const int row = h0 - PAD + sr;
        valid  = (col >= 0) && (col < WW) && (row >= 0) && (row < HH);
        pixoff = (size_t)(valid ? row * WW + col : 0) * KC;
        ldst   = &sh[(sr * 24 + sq) * AK];
        gbase  = interm + SLOT_ELEMS + (size_t)b * NCC * CHPLANE;
    } else {
        const int i  = t - BPTS;
        const int sm = i & 15;
        const int sr = i >> 4;
        valid  = true;
        pixoff = (size_t)((h0 + sr) * WW + (w0 + sm)) * KC;
        ldst   = &sh[(BPTS + sr * 16 + sm) * AK];
        gbase  = interm + (size_t)b * NCC * CHPLANE;
    }

    // invalid B points: zero their LDS slot once; they skip stores afterwards
    if (!valid) {
        const int4 z = {0, 0, 0, 0};
#pragma unroll
        for (int k = 0; k < 4; ++k) *(int4*)&ldst[k * 8] = z;
    }

    f32x4 acc[9][2];
#pragma unroll
    for (int dy = 0; dy < 9; ++dy) {
        acc[dy][0] = (f32x4){0.f, 0.f, 0.f, 0.f};
        acc[dy][1] = (f32x4){0.f, 0.f, 0.f, 0.f};
    }

    int4 vbuf[4];

#define LOAD_CHUNK(CH)                                                        \
    do {                                                                      \
        const _Float16* g_ = gbase + (size_t)(CH) * CHPLANE + pixoff;         \
        _Pragma("unroll")                                                     \
        for (int k = 0; k < 4; ++k) vbuf[k] = ((const int4*)g_)[k];           \
    } while (0)

#define STORE_CHUNK()                                                         \
    do {                                                                      \
        if (valid) {                                                          \
            _Pragma("unroll")                                                 \
            for (int k = 0; k < 4; ++k) *(int4*)&ldst[k * 8] = vbuf[k];       \
        }                                                                     \
    } while (0)

    LOAD_CHUNK(0);
    STORE_CHUNK();
    __syncthreads();

#pragma unroll 1
    for (int ch = 0; ch < NCC; ++ch) {
        if (ch + 1 < NCC) LOAD_CHUNK(ch + 1);   // stays in flight over MFMA phase

        // one output row per wave: 9 dy x 2 N-tiles
        {
            const half8 a = *(const half8*)&sh[(BPTS + wave * 16 + l15) * AK + quad * 8];
#pragma unroll
            for (int dy = 0; dy < 9; ++dy) {
                const int r = wave + dy;
                const half8 b0 = *(const half8*)&sh[(r * 24 + l15) * AK + quad * 8];
                acc[dy][0] = __builtin_amdgcn_mfma_f32_16x16x32_f16(a, b0, acc[dy][0], 0, 0, 0);
                const half8 b1 = *(const half8*)&sh[(r * 24 + 16 + l15) * AK + quad * 8];
                acc[dy][1] = __builtin_amdgcn_mfma_f32_16x16x32_f16(a, b1, acc[dy][1], 0, 0, 0);
            }
        }

        if (ch + 1 < NCC) {
            __syncthreads();    // everyone done reading chunk ch
            STORE_CHUNK();
            __syncthreads();    // chunk ch+1 visible
        }
    }
#undef LOAD_CHUNK
#undef STORE_CHUNK

    // ---- epilogue: D[p][q], p = quad*4+reg, q = l15+16*tt, dx = q - p ----
    const int h = h0 + wave;
#pragma unroll
    for (int dy = 0; dy < 9; ++dy) {
#pragma unroll
        for (int tt = 0; tt < 2; ++tt) {
#pragma unroll
            for (int reg = 0; reg < 4; ++reg) {
                const int p  = quad * 4 + reg;
                const int dx = l15 + 16 * tt - p;
                if (dx >= 0 && dx <= 8) {
                    out[(((size_t)b * KOUT + (dy * 9 + dx)) * HH + h) * WW + (w0 + p)] =
                        acc[dy][tt][reg];
                }
            }
        }
    }
}

extern "C" void kernel_launch(void* const* d_in, const int* in_sizes, int n_in,
                              void* d_out, int out_size, void* d_ws, size_t ws_size,
                              hipStream_t stream)
{
    (void)in_sizes; (void)n_in; (void)ws_size; (void)out_size;
    const float* i1 = (const float*)d_in[0];
    const float* i2 = (const float*)d_in[1];
    float* out = (float*)d_out;
    _Float16* interm = (_Float16*)d_ws;   // needs 2*SLOT_ELEMS*2B = 67.1 MB

    dim3 g1(HH, NCC, 2 * BB);             // (128, 8, 8) = 8192 blocks
    corr_pass1<<<g1, dim3(256), 0, stream>>>(i1, i2, interm);

    dim3 g2(WW / SW, HH / TH, BB);        // (8, 16, 4) = 512 blocks
    corr_pass2<<<g2, dim3(512), 0, stream>>>(interm, out);
}